// Round 19
// baseline (43.038 us; speedup 1.0000x reference)
//
#include <hip/hip_runtime.h>

#define H 1024
#define W 1024
#define M 15          // output rows per block (23 pipeline steps, 3x5 unroll)
#define WCOLS 56      // output cols per wave (64 lanes, 4-lane halo each side)
#define BCOLS 224     // 4 waves per block
#define RSTRIPS 69    // ceil(1024/15); last strip partial (o<H guard)
#define NBLK 1380     // 4 images x 5 col-strips x 69 row-strips

__device__ __forceinline__ float bpermf(int idx, float v) {
    return __int_as_float(__builtin_amdgcn_ds_bpermute(idx, __float_as_int(v)));
}

struct Lane {
    int ce, cn;           // clamped / nominal column
    bool colIn, outLane;
    int im2, im1, ip1, ip2, ifix;   // bpermute byte indices
};

struct St {               // per-lane register state (all static-indexed)
    float rh[5], gh[5], bh[5], kh[5];   // rgbk history (row = load row)
    float hs[5], hq[5];                 // horizontal 5-sums of luma, luma^2
    float S0w[5], S0x[5], S0y[5], S0z[5];   // per-row tap partial sums
    float S1w[5], S1x[5], S1y[5], S1z[5];
    float S2w[5], S2x[5], S2y[5], S2z[5];
    float vs_sv, vq_sv;                 // frozen vertical sums at row 1023
};

// One pipeline step. it: step index. Load row = y0-4+it (hist slot PH=it%5).
// DO_S: produce S for row c = y0-6+it. DO_OUT: emit output row o = y0-8+it.
template<int PH, bool DO_S, bool DO_OUT>
__device__ __forceinline__ void kstep(int it, int y0, const Lane& L,
    const float* __restrict__ pR, const float* __restrict__ pG,
    const float* __restrict__ pB, const float* __restrict__ pK,
    float* __restrict__ oR, float* __restrict__ oG, float* __restrict__ oB,
    St& S)
{
    const int  lr    = y0 - 4 + it;
    const int  lrc   = min(max(lr, 0), H - 1);
    const bool rowIn = ((unsigned)lr < (unsigned)H);
    const int  base  = lrc << 10;
    float r = pR[base + L.ce], g = pG[base + L.ce];
    float b = pB[base + L.ce], k = pK[base + L.ce];
    S.rh[PH] = r; S.gh[PH] = g; S.bh[PH] = b; S.kh[PH] = k;
    // zero-padded luma (box filter pads with 0 outside the image)
    float l = (rowIn && L.colIn)
                ? fmaf(0.2126f, r, fmaf(0.7152f, g, 0.0722f * b)) : 0.0f;
    float lm2 = bpermf(L.im2, l), lm1 = bpermf(L.im1, l);
    float lp1 = bpermf(L.ip1, l), lp2 = bpermf(L.ip2, l);
    S.hs[PH] = ((lm2 + lm1) + (lp1 + lp2)) + l;
    S.hq[PH] = ((lm2*lm2 + lm1*lm1) + (lp1*lp1 + lp2*lp2)) + l*l;

    if constexpr (DO_S) {
        const int c = y0 - 6 + it;          // row whose S we produce
        float vs = ((S.hs[0] + S.hs[1]) + (S.hs[2] + S.hs[3])) + S.hs[4];
        float vq = ((S.hq[0] + S.hq[1]) + (S.hq[2] + S.hq[3])) + S.hq[4];
        if (c == H - 1) { S.vs_sv = vs; S.vq_sv = vq; }   // bottom edge-
        if (c >  H - 1) { vs = S.vs_sv; vq = S.vq_sv; }   // replicate freeze
        float mean = vs * 0.04f, msq = vq * 0.04f;
        float var  = fabsf(msq - mean * mean);
        constexpr int PC = (PH + 3) % 5;    // slot of row c
        float w = __expf(-var * 64.0f * S.kh[PC]);
        w = bpermf(L.ifix, w);              // x edge-replication of weights
        float pr = w * S.rh[PC], pg = w * S.gh[PC], pb = w * S.bh[PC];
        float w_m1  = bpermf(L.im1, w),  w_p1  = bpermf(L.ip1, w);
        float w_m2  = bpermf(L.im2, w),  w_p2  = bpermf(L.ip2, w);
        float pr_m1 = bpermf(L.im1, pr), pr_p1 = bpermf(L.ip1, pr);
        float pr_m2 = bpermf(L.im2, pr), pr_p2 = bpermf(L.ip2, pr);
        float pg_m1 = bpermf(L.im1, pg), pg_p1 = bpermf(L.ip1, pg);
        float pg_m2 = bpermf(L.im2, pg), pg_p2 = bpermf(L.ip2, pg);
        float pb_m1 = bpermf(L.im1, pb), pb_p1 = bpermf(L.ip1, pb);
        float pb_m2 = bpermf(L.im2, pb), pb_p2 = bpermf(L.ip2, pb);
        S.S0w[PH] = w;             S.S0x[PH] = pr;
        S.S0y[PH] = pg;            S.S0z[PH] = pb;
        S.S1w[PH] = w_m1 + w_p1;   S.S1x[PH] = pr_m1 + pr_p1;
        S.S1y[PH] = pg_m1 + pg_p1; S.S1z[PH] = pb_m1 + pb_p1;
        S.S2w[PH] = w_m2 + w_p2;   S.S2x[PH] = pr_m2 + pr_p2;
        S.S2y[PH] = pg_m2 + pg_p2; S.S2z[PH] = pb_m2 + pb_p2;
    }

    if constexpr (DO_OUT) {
        const int o = y0 - 8 + it;          // output row
        constexpr int PO = (PH + 1) % 5;    // rgbk slot of row o
        float ko = S.kh[PO];
        float t  = __expf(-2.56f * (1.0f - ko));   // t^(dx^2+dy^2) base
        float t1 = t, t4 = (t * t) * (t * t);
        float ctrR = S.rh[PO], ctrG = S.gh[PO], ctrB = S.bh[PO];
        float aR = 0.f, aG = 0.f, aB = 0.f, aW = 0.f;
        // rows o+dy, dy=-2..2 -> S slots (PH+3+dy)%5, row factor t^(dy^2)
#define ROWTERM(SL, F)                                                    \
        { float rw = S.S0w[SL] + t1 * S.S1w[SL] + t4 * S.S2w[SL];         \
          float rx = S.S0x[SL] + t1 * S.S1x[SL] + t4 * S.S2x[SL];         \
          float ry = S.S0y[SL] + t1 * S.S1y[SL] + t4 * S.S2y[SL];         \
          float rz = S.S0z[SL] + t1 * S.S1z[SL] + t4 * S.S2z[SL];         \
          aW = fmaf(F, rw, aW); aR = fmaf(F, rx, aR);                     \
          aG = fmaf(F, ry, aG); aB = fmaf(F, rz, aB); }
        ROWTERM((PH + 1) % 5, t4)
        ROWTERM((PH + 2) % 5, t1)
        ROWTERM((PH + 3) % 5, 1.0f)
        ROWTERM((PH + 4) % 5, t1)
        ROWTERM(PH,           t4)
#undef ROWTERM
        float cb = 16.0f + ko * (0.001f - 16.0f);   // center boost
        aR += cb * ctrR; aG += cb * ctrG; aB += cb * ctrB; aW += cb;
        float inv = __builtin_amdgcn_rcpf(aW);
        if (L.outLane && o < H) {
            int off = (o << 10) + L.cn;
            oR[off] = ctrR + ko * (aR * inv - ctrR);
            oG[off] = ctrG + ko * (aG * inv - ctrG);
            oB[off] = ctrB + ko * (aB * inv - ctrB);
        }
    }
}

__global__ void kuwahara_kernel(const float* __restrict__ inp,
                                float* __restrict__ out) {
    // ---- XCD-aware BIJECTIVE swizzle over 1380 blocks (1380 = 8q+r, q=172,r=4):
    // XCDs 0..3 own 173 contiguous lin each, XCDs 4..7 own 172.
    int bid = blockIdx.x;
    int x   = bid & 7, idx = bid >> 3;
    int lin = (x < 4) ? x * 173 + idx : 4 * 173 + (x - 4) * 172 + idx;
    int img    = lin / (5 * RSTRIPS);
    int r2     = lin - img * (5 * RSTRIPS);
    int cstrip = r2 / RSTRIPS;
    int rstrip = r2 - cstrip * RSTRIPS;
    int y0 = rstrip * M;
    if (y0 >= H) return;

    const float* __restrict__ pR = inp + ((size_t)(4*img + 0) << 20);
    const float* __restrict__ pG = inp + ((size_t)(4*img + 1) << 20);
    const float* __restrict__ pB = inp + ((size_t)(4*img + 2) << 20);
    const float* __restrict__ pK = inp + ((size_t)(4*img + 3) << 20);
    float* __restrict__ oR = out + ((size_t)(3*img + 0) << 20);
    float* __restrict__ oG = out + ((size_t)(3*img + 1) << 20);
    float* __restrict__ oB = out + ((size_t)(3*img + 2) << 20);

    const int tid = threadIdx.x;
    const int wi  = tid >> 6;
    const int ln  = tid & 63;

    Lane L;
    L.cn     = cstrip * BCOLS + wi * WCOLS - 4 + ln;
    L.ce     = min(max(L.cn, 0), W - 1);
    L.colIn  = ((unsigned)L.cn < (unsigned)W);
    L.outLane= (ln >= 4) && (ln < 60) && L.colIn;
    L.im2  = (ln - 2) << 2;   // bpermute wraps mod 64; wrapped lanes unused
    L.im1  = (ln - 1) << 2;
    L.ip1  = (ln + 1) << 2;
    L.ip2  = (ln + 2) << 2;
    L.ifix = (ln - L.cn + L.ce) << 2;   // lane of clamped column

    St S;
    S.vs_sv = 0.f; S.vq_sv = 0.f;

    // ---- pipeline warmup ----
    kstep<0, false, false>(0, y0, L, pR, pG, pB, pK, oR, oG, oB, S);
    kstep<1, false, false>(1, y0, L, pR, pG, pB, pK, oR, oG, oB, S);
    kstep<2, false, false>(2, y0, L, pR, pG, pB, pK, oR, oG, oB, S);
    kstep<3, false, false>(3, y0, L, pR, pG, pB, pK, oR, oG, oB, S);
    kstep<4, true,  false>(4, y0, L, pR, pG, pB, pK, oR, oG, oB, S);
    kstep<0, true,  false>(5, y0, L, pR, pG, pB, pK, oR, oG, oB, S);
    kstep<1, true,  false>(6, y0, L, pR, pG, pB, pK, oR, oG, oB, S);
    if (y0 == 0) {
        // top edge-replication: S(row -1) := S(row -2) := S(row 0) (slot 1)
#define CPY(A) S.A[0] = S.A[1]; S.A[4] = S.A[1];
        CPY(S0w) CPY(S0x) CPY(S0y) CPY(S0z)
        CPY(S1w) CPY(S1x) CPY(S1y) CPY(S1z)
        CPY(S2w) CPY(S2x) CPY(S2y) CPY(S2z)
#undef CPY
    }
    kstep<2, true,  false>(7, y0, L, pR, pG, pB, pK, oR, oG, oB, S);

    // ---- main loop: 15 output rows, unrolled by 5 (static history phases) ----
#pragma unroll 1
    for (int itb = 8; itb < 8 + M; itb += 5) {
        kstep<3, true, true>(itb + 0, y0, L, pR, pG, pB, pK, oR, oG, oB, S);
        kstep<4, true, true>(itb + 1, y0, L, pR, pG, pB, pK, oR, oG, oB, S);
        kstep<0, true, true>(itb + 2, y0, L, pR, pG, pB, pK, oR, oG, oB, S);
        kstep<1, true, true>(itb + 3, y0, L, pR, pG, pB, pK, oR, oG, oB, S);
        kstep<2, true, true>(itb + 4, y0, L, pR, pG, pB, pK, oR, oG, oB, S);
    }
}

extern "C" void kernel_launch(void* const* d_in, const int* in_sizes, int n_in,
                              void* d_out, int out_size, void* d_ws, size_t ws_size,
                              hipStream_t stream) {
    const float* inp = (const float*)d_in[0];
    float* out = (float*)d_out;
    hipLaunchKernelGGL(kuwahara_kernel, dim3(NBLK), dim3(256), 0, stream, inp, out);
}

// Round 20
// 36.258 us; speedup vs baseline: 1.1870x; 1.1870x over previous
//
#include <hip/hip_runtime.h>

#define H 1024
#define W 1024
#define TILE 32
#define SR 40    // hsum rows: TILE + 8 (halo4)
#define SC 36    // hsum cols: TILE + 4
#define VR 36    // vw rows:   TILE + 4
#define VC 36    // vw cols:   TILE + 4

// LDS: s_su 40*36*8 = 11520 B + s_vw 36*36*16 = 20736 B -> 32256 B -> 5 blocks/CU.

__global__ __launch_bounds__(256)
void kuwahara_kernel(const float* __restrict__ inp, float* __restrict__ out) {
    __shared__ float2 s_su[SR][SC];   // (hsum luma, hsum luma^2), halo4 rows
    __shared__ float4 s_vw[VR][VC];   // (r, g, b, k->weight), edge-replicated

    const int tid = threadIdx.x;

    // ---- XCD-aware swizzle: each XCD owns 512 contiguous tiles (x-fastest) ----
    unsigned wg  = blockIdx.x;          // grid = 4096 linear blocks
    unsigned lin = (wg & 7u) * 512u + (wg >> 3);
    const int n  = lin >> 10;
    const int y0 = ((lin >> 5) & 31) * TILE;
    const int x0 = (lin & 31) * TILE;

    const float* __restrict__ pR = inp + ((size_t)(4*n + 0) << 20);
    const float* __restrict__ pG = inp + ((size_t)(4*n + 1) << 20);
    const float* __restrict__ pB = inp + ((size_t)(4*n + 2) << 20);
    const float* __restrict__ pK = inp + ((size_t)(4*n + 3) << 20);

    const int tx  = tid & 31;   // column within tile
    const int tg  = tid >> 5;   // row-group: owns rows 4*tg .. 4*tg+3
    const int gx  = x0 + tx;
    const int pr0 = tg << 2;

    // ---- k at this thread's 4 output pixels (fp32 exact; L1/L2-resident) ----
    float kc[4];
#pragma unroll
    for (int p = 0; p < 4; ++p)
        kc[p] = pK[((y0 + pr0 + p) << 10) + gx];

    // ---- stage 1 (fully fused, SINGLE load of rgbk per halo pixel):
    // luma + horizontal 5-sums via __shfl_down, AND s_vw fill from the same
    // registers. 10 lanes/row (one 4-px quad each); 6 rows/wave; 2 passes.
    {
        const int lane = tid & 63;
        const int wid  = tid >> 6;
        const int rloc = lane / 10;            // 0..5 active, 6 idle
        const int qq   = lane - rloc * 10;     // quad index 0..9
        const int gcs  = x0 - 4 + (qq << 2);
#pragma unroll
        for (int pass = 0; pass < 2; ++pass) {
            int row = pass * 24 + wid * 6 + rloc;
            bool act = (rloc < 6) && (row < SR);
            bool vwrow = act && (row >= 2) && (row < SR - 2);
            float l0 = 0.f, l1 = 0.f, l2 = 0.f, l3 = 0.f;
            float rr[4], gg[4], bb[4], kk[4];
            if (act) {
                int gy = y0 - 4 + row;
                int cy = min(max(gy, 0), H - 1);
                const int base = cy << 10;
                if (gcs >= 0 && gcs <= W - 4) {         // x-interior: vector
                    float4 r4 = *(const float4*)(pR + base + gcs);
                    float4 g4 = *(const float4*)(pG + base + gcs);
                    float4 b4 = *(const float4*)(pB + base + gcs);
                    rr[0]=r4.x; rr[1]=r4.y; rr[2]=r4.z; rr[3]=r4.w;
                    gg[0]=g4.x; gg[1]=g4.y; gg[2]=g4.z; gg[3]=g4.w;
                    bb[0]=b4.x; bb[1]=b4.y; bb[2]=b4.z; bb[3]=b4.w;
                    if (vwrow) {
                        float4 k4 = *(const float4*)(pK + base + gcs);
                        kk[0]=k4.x; kk[1]=k4.y; kk[2]=k4.z; kk[3]=k4.w;
                    }
                } else {                                 // x-border: clamped
#pragma unroll
                    for (int e = 0; e < 4; ++e) {
                        int cx = min(max(gcs + e, 0), W - 1);
                        rr[e] = pR[base + cx]; gg[e] = pG[base + cx];
                        bb[e] = pB[base + cx];
                        kk[e] = vwrow ? pK[base + cx] : 0.f;
                    }
                }
                bool rowIn = ((unsigned)gy < (unsigned)H);
                float lv[4];
#pragma unroll
                for (int e = 0; e < 4; ++e) {
                    bool colIn = ((unsigned)(gcs + e) < (unsigned)W);
                    lv[e] = (rowIn && colIn)
                        ? fmaf(0.2126f, rr[e], fmaf(0.7152f, gg[e], 0.0722f * bb[e]))
                        : 0.0f;                          // zero pad rows AND cols
                }
                l0 = lv[0]; l1 = lv[1]; l2 = lv[2]; l3 = lv[3];
            }
            // neighbor quad's luma (same row: qq<=8 pulls from qq+1)
            float l4 = __shfl_down(l0, 1, 64);
            float l5 = __shfl_down(l1, 1, 64);
            float l6 = __shfl_down(l2, 1, 64);
            float l7 = __shfl_down(l3, 1, 64);
            if (act && qq < 9) {
                float s0 = ((l0 + l1) + (l2 + l3)) + l4;
                float s1 = s0 - l0 + l5;
                float s2 = s1 - l1 + l6;
                float s3 = s2 - l2 + l7;
                float m0=l0*l0, m1=l1*l1, m2=l2*l2, m3=l3*l3;
                float m4=l4*l4, m5=l5*l5, m6=l6*l6, m7=l7*l7;
                float u0 = ((m0 + m1) + (m2 + m3)) + m4;
                float u1 = u0 - m0 + m5;
                float u2 = u1 - m1 + m6;
                float u3 = u2 - m2 + m7;
                int c = qq << 2;
                *(float4*)&s_su[row][c]     = make_float4(s0, u0, s1, u1);
                *(float4*)&s_su[row][c + 2] = make_float4(s2, u2, s3, u3);
            }
            if (vwrow) {                // s_vw from SAME regs; rotated write
#pragma unroll                          // order spreads the 16-bank qq stride
                for (int e = 0; e < 4; ++e) {
                    int er = (e + qq) & 3;
                    int iv = (qq << 2) + er - 2;
                    if ((unsigned)iv < (unsigned)VC)
                        s_vw[row - 2][iv] = make_float4(rr[er], gg[er], bb[er], kk[er]);
                }
            }
        }
    }
    __syncthreads();

    // ---- spatial-falloff constants (depend only on kc) ----
    float t1[4], t4[4];
#pragma unroll
    for (int p = 0; p < 4; ++p) {
        float t = __expf(-2.56f * (1.0f - kc[p]));   // t^(dx^2+dy^2) base
        t1[p] = t;
        t4[p] = (t * t) * (t * t);
    }

    // ---- stage 3: vertical 5-sum -> variance -> weight. 2-col x 4-row tasks,
    // sliding vertical sums: 8 b128 reads -> 8 weights. 162 tasks, single pass.
    if (tid < 162) {
        int j4r = tid / 18, q = tid - j4r * 18;
        int j4  = j4r << 2;                     // rows j4 .. j4+3
        int c   = q << 1;                       // cols c, c+1
        int g0  = x0 - 2 + c;
        bool okx = (g0 >= 0) && (g0 + 1 <= W - 1);
        bool oky = (y0 - 2 + j4 >= 0) && (y0 - 2 + j4 + 3 <= H - 1);
        if (okx && oky) {                       // fast: all 8 centers unclamped
            float4 r0 = *(const float4*)&s_su[j4 + 0][c];
            float4 r1 = *(const float4*)&s_su[j4 + 1][c];
            float4 r2 = *(const float4*)&s_su[j4 + 2][c];
            float4 r3 = *(const float4*)&s_su[j4 + 3][c];
            float4 r4 = *(const float4*)&s_su[j4 + 4][c];
            float4 r5 = *(const float4*)&s_su[j4 + 5][c];
            float4 r6 = *(const float4*)&s_su[j4 + 6][c];
            float4 r7 = *(const float4*)&s_su[j4 + 7][c];
            float sx = (((r0.x + r1.x) + (r2.x + r3.x)) + r4.x);
            float sy = (((r0.y + r1.y) + (r2.y + r3.y)) + r4.y);
            float sz = (((r0.z + r1.z) + (r2.z + r3.z)) + r4.z);
            float sw = (((r0.w + r1.w) + (r2.w + r3.w)) + r4.w);
#pragma unroll
            for (int jj = 0; jj < 4; ++jj) {
                {
                    float mean = sx * 0.04f, msq = sy * 0.04f;
                    float var  = fabsf(msq - mean * mean);
                    s_vw[j4 + jj][c].w = __expf(-var * 64.0f * s_vw[j4 + jj][c].w);
                }
                {
                    float mean = sz * 0.04f, msq = sw * 0.04f;
                    float var  = fabsf(msq - mean * mean);
                    s_vw[j4 + jj][c + 1].w = __expf(-var * 64.0f * s_vw[j4 + jj][c + 1].w);
                }
                if (jj < 3) {                   // slide window down one row
                    const float4 rl = (jj == 0) ? r0 : (jj == 1) ? r1 : r2;
                    const float4 rh = (jj == 0) ? r5 : (jj == 1) ? r6 : r7;
                    sx += rh.x - rl.x;  sy += rh.y - rl.y;
                    sz += rh.z - rl.z;  sw += rh.w - rl.w;
                }
            }
        } else {                                // border: per-output scalar
#pragma unroll
            for (int jj = 0; jj < 4; ++jj) {
                int j2 = j4 + jj;
                int gyc = min(max(y0 - 2 + j2, 0), H - 1);
                int js  = gyc - y0 + 2;
#pragma unroll
                for (int e = 0; e < 2; ++e) {
                    int is = min(max(g0 + e, 0), W - 1) - x0 + 2;
                    float ss = 0.f, sq = 0.f;
#pragma unroll
                    for (int r = 0; r < 5; ++r) {
                        float2 v = s_su[js + r][is];
                        ss += v.x; sq += v.y;
                    }
                    float mean = ss * 0.04f, msq = sq * 0.04f;
                    float var  = fabsf(msq - mean * mean);
                    s_vw[j2][c + e].w = __expf(-var * 64.0f * s_vw[j2][c + e].w);
                }
            }
        }
    }
    __syncthreads();

    // ---- stage 4: 25-tap filter; factorized row sums shared across 4 px ----
    float accR[4], accG[4], accB[4], accW[4];
    float ctrR[4], ctrG[4], ctrB[4];
#pragma unroll
    for (int p = 0; p < 4; ++p) { accR[p] = accG[p] = accB[p] = accW[p] = 0.f; }

#pragma unroll
    for (int r = 0; r < 8; ++r) {
        const float4* row = &s_vw[pr0 + r][tx];      // single base, imm offsets
        float4 a0 = row[0], a1 = row[1], a2 = row[2], a3 = row[3], a4 = row[4];
        // partial sums by |dx|: S0 (dx=0), S1 (|dx|=1), S2 (|dx|=2)
        float S0w = a2.w;
        float S0x = a2.w * a2.x, S0y = a2.w * a2.y, S0z = a2.w * a2.z;
        float S1w = a1.w + a3.w;
        float S1x = a1.w * a1.x + a3.w * a3.x;
        float S1y = a1.w * a1.y + a3.w * a3.y;
        float S1z = a1.w * a1.z + a3.w * a3.z;
        float S2w = a0.w + a4.w;
        float S2x = a0.w * a0.x + a4.w * a4.x;
        float S2y = a0.w * a0.y + a4.w * a4.y;
        float S2z = a0.w * a0.z + a4.w * a4.z;
#pragma unroll
        for (int p = 0; p < 4; ++p) {
            const int dy = r - 2 - p;                // compile-time after unroll
            if (dy < -2 || dy > 2) continue;
            const int ady = dy < 0 ? -dy : dy;
            float rw = S0w + t1[p] * S1w + t4[p] * S2w;
            float rx = S0x + t1[p] * S1x + t4[p] * S2x;
            float ry = S0y + t1[p] * S1y + t4[p] * S2y;
            float rz = S0z + t1[p] * S1z + t4[p] * S2z;
            if (ady == 0) {                          // center row: capture rgb
                ctrR[p] = a2.x; ctrG[p] = a2.y; ctrB[p] = a2.z;
                accR[p] += rx; accG[p] += ry; accB[p] += rz; accW[p] += rw;
            } else {
                float rf = (ady == 1) ? t1[p] : t4[p];
                accR[p] += rf * rx; accG[p] += rf * ry;
                accB[p] += rf * rz; accW[p] += rf * rw;
            }
        }
    }

    float* __restrict__ oR = out + ((size_t)(3*n + 0) << 20);
    float* __restrict__ oG = out + ((size_t)(3*n + 1) << 20);
    float* __restrict__ oB = out + ((size_t)(3*n + 2) << 20);
#pragma unroll
    for (int p = 0; p < 4; ++p) {
        float cb = 16.0f + kc[p] * (0.001f - 16.0f); // center boost
        accR[p] += cb * ctrR[p];
        accG[p] += cb * ctrG[p];
        accB[p] += cb * ctrB[p];
        accW[p] += cb;
        float inv = __builtin_amdgcn_rcpf(accW[p]);
        int off = ((y0 + pr0 + p) << 10) + gx;
        oR[off] = ctrR[p] + kc[p] * (accR[p] * inv - ctrR[p]);
        oG[off] = ctrG[p] + kc[p] * (accG[p] * inv - ctrG[p]);
        oB[off] = ctrB[p] + kc[p] * (accB[p] * inv - ctrB[p]);
    }
}

extern "C" void kernel_launch(void* const* d_in, const int* in_sizes, int n_in,
                              void* d_out, int out_size, void* d_ws, size_t ws_size,
                              hipStream_t stream) {
    const float* inp = (const float*)d_in[0];
    float* out = (float*)d_out;
    hipLaunchKernelGGL(kuwahara_kernel, dim3(4096), dim3(256), 0, stream, inp, out);
}